// Round 1
// baseline (4898.203 us; speedup 1.0000x reference)
//
#include <hip/hip_runtime.h>
#include <stdint.h>

// Problem constants
#define BB 64
#define SS 512
#define EE 128
#define HH 256
#define KK 20
#define NEGV -9999.0f
#define SOS_IDX 19

typedef unsigned int u32;

__device__ __forceinline__ float bf_lo(u32 u){ return __uint_as_float(u << 16); }
__device__ __forceinline__ float bf_hi(u32 u){ return __uint_as_float(u & 0xffff0000u); }
__device__ __forceinline__ unsigned short f2b(float f){
  u32 u = __float_as_uint(f);
  u = (u + 0x7fffu + ((u >> 16) & 1u)) >> 16;  // RNE
  return (unsigned short)u;
}
__device__ __forceinline__ float b2f(unsigned short s){ return __uint_as_float(((u32)s) << 16); }
__device__ __forceinline__ float sigm(float x){ return 1.0f / (1.0f + __expf(-x)); }

// ---- K0a: pack W_hh (f32 [1024][256]) -> bf16 wp[d][kb(32)][row(1024)][8]
__global__ void prep_whh(const float* __restrict__ whh_f, const float* __restrict__ whh_b,
                         unsigned short* __restrict__ wp){
  int id = blockIdx.x * 256 + threadIdx.x;      // 2*1024*256 = 524288
  if (id >= 2 * 1024 * 256) return;
  int d = id >> 18;
  int rem = id & 262143;
  int row = rem >> 8;
  int k = rem & 255;
  const float* w = d ? whh_b : whh_f;
  float v = w[row * 256 + k];
  int kb = k >> 3, i = k & 7;
  wp[(((size_t)d * 32 + kb) * 1024 + row) * 8 + i] = f2b(v);
}

// ---- K0b: transpose W_ih -> wt[k(128)][2048] f32 (cols 0..1023 fwd, 1024..2047 bwd)
__global__ void prep_wih(const float* __restrict__ wih_f, const float* __restrict__ wih_b,
                         float* __restrict__ wt){
  int id = blockIdx.x * 256 + threadIdx.x;      // 2*1024*128 = 262144
  if (id >= 262144) return;
  int d = id >> 17;
  int rem = id & 131071;
  int col = rem >> 7;
  int k = rem & 127;
  const float* w = d ? wih_b : wih_f;
  wt[(size_t)k * 2048 + d * 1024 + col] = w[col * 128 + k];
}

// ---- K1: xg = embed[word] @ W_ih.T + b, both dirs, stored bf16.
// WG = 256 thr covers 16 rows x 1024 cols (cb selects fwd/bwd half).
__global__ __launch_bounds__(256) void xg_gemm(const int* __restrict__ word_seq,
    const float* __restrict__ embed, const float* __restrict__ wt,
    const float* __restrict__ b_f, const float* __restrict__ b_b,
    unsigned short* __restrict__ xg){
  __shared__ __align__(16) float xs[16][128];
  int rb = blockIdx.x >> 1, cb = blockIdx.x & 1;
  int tid = threadIdx.x;
  {
    int r = tid >> 4, kq = (tid & 15) * 8;
    int bs = rb * 16 + r;
    int w = word_seq[bs];
    const float* er = embed + (size_t)w * 128 + kq;
    float4 a = *(const float4*)er;
    float4 b = *(const float4*)(er + 4);
    *(float4*)&xs[r][kq] = a;
    *(float4*)&xs[r][kq + 4] = b;
  }
  __syncthreads();
  int co = tid * 4;
  const float* bias = cb ? b_b : b_f;
  float4 bv = *(const float4*)(bias + co);
  float4 acc[16];
  #pragma unroll
  for (int r = 0; r < 16; r++) acc[r] = bv;
  const float* wptr = wt + cb * 1024 + co;
  for (int k = 0; k < 128; k++){
    float4 w4 = *(const float4*)(wptr + (size_t)k * 2048);
    #pragma unroll
    for (int r = 0; r < 16; r++){
      float xv = xs[r][k];
      acc[r].x += xv * w4.x; acc[r].y += xv * w4.y;
      acc[r].z += xv * w4.z; acc[r].w += xv * w4.w;
    }
  }
  unsigned short* base = xg + (size_t)cb * ((size_t)BB * SS * 1024);
  #pragma unroll
  for (int r = 0; r < 16; r++){
    int bs = rb * 16 + r;
    unsigned short* o = base + (size_t)bs * 1024 + co;
    ushort4 pk;
    pk.x = f2b(acc[r].x); pk.y = f2b(acc[r].y);
    pk.z = f2b(acc[r].z); pk.w = f2b(acc[r].w);
    *(ushort4*)o = pk;
  }
}

// ---- K2: sequential LSTM, one WG per (batch, dir). Thread j owns hidden unit j.
// Weights bf16 streamed from L2 (512KB/step/WG), h state f32 in LDS, c in reg.
__global__ __launch_bounds__(256) void lstm_seq(const int* __restrict__ lengths,
    const unsigned short* __restrict__ wp, const unsigned short* __restrict__ xg,
    unsigned short* __restrict__ rnn){
  int bx = blockIdx.x;
  int b = bx & 63, d = bx >> 6;
  int j = threadIdx.x;
  int l = lengths[b];
  const unsigned short* wpd = wp + (size_t)d * 262144;
  const unsigned short* xgd = xg + (size_t)d * ((size_t)BB * SS * 1024) + (size_t)b * SS * 1024;
  __shared__ __align__(16) float hl[256];
  hl[j] = 0.f;
  float c = 0.f;
  // zero-fill padded outputs (reference: masked steps output 0)
  for (int s = l; s < SS; s++) rnn[((size_t)b * SS + s) * 512 + d * 256 + j] = 0;
  __syncthreads();
  for (int t = 0; t < l; t++){
    int s = d ? (l - 1 - t) : t;
    const unsigned short* xr = xgd + (size_t)s * 1024 + j;
    float a0 = b2f(xr[0]);
    float a1 = b2f(xr[256]);
    float a2 = b2f(xr[512]);
    float a3 = b2f(xr[768]);
    #pragma unroll 8
    for (int kb = 0; kb < 32; kb++){
      const unsigned short* wb = wpd + kb * 8192;
      uint4 w0 = *(const uint4*)(wb + j * 8);
      uint4 w1 = *(const uint4*)(wb + (256 + j) * 8);
      uint4 w2 = *(const uint4*)(wb + (512 + j) * 8);
      uint4 w3 = *(const uint4*)(wb + (768 + j) * 8);
      float4 h0 = *(const float4*)&hl[kb * 8];
      float4 h1 = *(const float4*)&hl[kb * 8 + 4];
      a0 += bf_lo(w0.x)*h0.x + bf_hi(w0.x)*h0.y + bf_lo(w0.y)*h0.z + bf_hi(w0.y)*h0.w
          + bf_lo(w0.z)*h1.x + bf_hi(w0.z)*h1.y + bf_lo(w0.w)*h1.z + bf_hi(w0.w)*h1.w;
      a1 += bf_lo(w1.x)*h0.x + bf_hi(w1.x)*h0.y + bf_lo(w1.y)*h0.z + bf_hi(w1.y)*h0.w
          + bf_lo(w1.z)*h1.x + bf_hi(w1.z)*h1.y + bf_lo(w1.w)*h1.z + bf_hi(w1.w)*h1.w;
      a2 += bf_lo(w2.x)*h0.x + bf_hi(w2.x)*h0.y + bf_lo(w2.y)*h0.z + bf_hi(w2.y)*h0.w
          + bf_lo(w2.z)*h1.x + bf_hi(w2.z)*h1.y + bf_lo(w2.w)*h1.z + bf_hi(w2.w)*h1.w;
      a3 += bf_lo(w3.x)*h0.x + bf_hi(w3.x)*h0.y + bf_lo(w3.y)*h0.z + bf_hi(w3.y)*h0.w
          + bf_lo(w3.z)*h1.x + bf_hi(w3.z)*h1.y + bf_lo(w3.w)*h1.z + bf_hi(w3.w)*h1.w;
    }
    float ig = sigm(a0), fg = sigm(a1), gg = tanhf(a2), og = sigm(a3);
    c = fg * c + ig * gg;
    float ht = og * tanhf(c);
    rnn[((size_t)b * SS + s) * 512 + d * 256 + j] = f2b(ht);
    __syncthreads();
    hl[j] = ht;
    __syncthreads();
  }
}

// ---- K3: feats = rnn_out @ lin_W.T + lin_b  (one thread per (row,col))
__global__ void feat_gemv(const unsigned short* __restrict__ rnn,
    const float* __restrict__ linW, const float* __restrict__ linb,
    float* __restrict__ feats){
  int id = blockIdx.x * 256 + threadIdx.x;
  if (id >= BB * SS * KK) return;
  int row = id / 20;
  int col = id - row * 20;
  const unsigned short* rr = rnn + (size_t)row * 512;
  const float* wr = linW + col * 512;
  float acc = linb[col];
  for (int k8 = 0; k8 < 64; k8++){
    uint4 rv = *(const uint4*)(rr + k8 * 8);
    float4 wa = *(const float4*)(wr + k8 * 8);
    float4 wb = *(const float4*)(wr + k8 * 8 + 4);
    acc += bf_lo(rv.x)*wa.x + bf_hi(rv.x)*wa.y + bf_lo(rv.y)*wa.z + bf_hi(rv.y)*wa.w
         + bf_lo(rv.z)*wb.x + bf_hi(rv.z)*wb.y + bf_lo(rv.w)*wb.z + bf_hi(rv.w)*wb.w;
  }
  feats[id] = acc;
}

// ---- K4: CRF numerator + forward scan. One WG (1 wave) per batch.
__global__ __launch_bounds__(64) void crf_kernel(const int* __restrict__ tags,
    const int* __restrict__ lengths, const float* __restrict__ trans,
    const float* __restrict__ feats, float* __restrict__ out){
  int b = blockIdx.x, tid = threadIdx.x;
  __shared__ float tr[400];
  __shared__ float sc[20];
  for (int i = tid; i < 400; i += 64) tr[i] = trans[i];
  __syncthreads();
  int l = lengths[b];
  const int* tg = tags + b * SS;
  const float* fb = feats + (size_t)b * SS * 20;
  // numerator
  float p = 0.f;
  for (int s = tid; s < SS; s += 64){
    if (s < l){
      int cur = tg[s];
      int prev = s ? tg[s - 1] : SOS_IDX;
      p += fb[s * 20 + cur] + tr[cur * 20 + prev];
    }
  }
  #pragma unroll
  for (int off = 32; off; off >>= 1) p += __shfl_down(p, off);
  if (tid < 20) sc[tid] = (tid == SOS_IDX) ? 0.f : NEGV;
  __syncthreads();
  for (int s = 0; s < l; s++){
    float nv = 0.f;
    if (tid < 20){
      float em = fb[s * 20 + tid];
      const float* trow = &tr[tid * 20];
      float v[20];
      float m = -1e30f;
      #pragma unroll
      for (int jj = 0; jj < 20; jj++){ v[jj] = sc[jj] + trow[jj]; m = fmaxf(m, v[jj]); }
      float ssum = 0.f;
      #pragma unroll
      for (int jj = 0; jj < 20; jj++) ssum += __expf(v[jj] - m);
      nv = em + m + __logf(ssum);
    }
    __syncthreads();
    if (tid < 20) sc[tid] = nv;
    __syncthreads();
  }
  if (tid == 0){
    float m = -1e30f;
    #pragma unroll
    for (int i = 0; i < 20; i++) m = fmaxf(m, sc[i]);
    float ssum = 0.f;
    #pragma unroll
    for (int i = 0; i < 20; i++) ssum += __expf(sc[i] - m);
    out[b] = (m + __logf(ssum)) - p;
  }
}

extern "C" void kernel_launch(void* const* d_in, const int* in_sizes, int n_in,
                              void* d_out, int out_size, void* d_ws, size_t ws_size,
                              hipStream_t stream){
  const int*   word_seq = (const int*)d_in[0];
  const int*   tags     = (const int*)d_in[1];
  const int*   lengths  = (const int*)d_in[2];
  const float* embed    = (const float*)d_in[3];
  const float* wih_f    = (const float*)d_in[4];
  const float* whh_f    = (const float*)d_in[5];
  const float* b_f      = (const float*)d_in[6];
  const float* wih_b    = (const float*)d_in[7];
  const float* whh_b    = (const float*)d_in[8];
  const float* b_b      = (const float*)d_in[9];
  const float* linW     = (const float*)d_in[10];
  const float* linb     = (const float*)d_in[11];
  const float* trans    = (const float*)d_in[12];
  float* out = (float*)d_out;

  // workspace layout (total ~165 MB)
  char* ws = (char*)d_ws;
  unsigned short* wp    = (unsigned short*)ws;                                   // 1 MB
  float*          wt    = (float*)(ws + (1ull << 20));                           // 1 MB
  unsigned short* xg    = (unsigned short*)(ws + (2ull << 20));                  // 128 MB
  unsigned short* rnn   = (unsigned short*)(ws + (2ull << 20) + 134217728ull);   // 32 MB
  float*          feats = (float*)(ws + (2ull << 20) + 134217728ull + 33554432ull); // 2.5 MB

  prep_whh<<<dim3(2048), dim3(256), 0, stream>>>(whh_f, whh_b, wp);
  prep_wih<<<dim3(1024), dim3(256), 0, stream>>>(wih_f, wih_b, wt);
  xg_gemm<<<dim3(4096), dim3(256), 0, stream>>>(word_seq, embed, wt, b_f, b_b, xg);
  lstm_seq<<<dim3(128), dim3(256), 0, stream>>>(lengths, wp, xg, rnn);
  feat_gemv<<<dim3(2560), dim3(256), 0, stream>>>(rnn, linW, linb, feats);
  crf_kernel<<<dim3(64), dim3(64), 0, stream>>>(tags, lengths, trans, feats, out);
}